// Round 7
// baseline (504.232 us; speedup 1.0000x reference)
//
#include <hip/hip_runtime.h>
#include <hip/hip_bf16.h>
#include <hip/hip_fp16.h>
#include <math.h>

// Problem constants
#define DD   1024
#define EE   8
#define HH   512
#define NTOK 16384        // B*T
#define NG   16           // (expert, slot) groups
#define MAXMT 24          // max 128-row tiles per group (n_g ~ 2048 +- ~200)

typedef __attribute__((ext_vector_type(8))) short short8;   // 8 bf16
typedef __attribute__((ext_vector_type(4))) float floatx4;  // MFMA C/D frag

__device__ __forceinline__ ushort f2bfu(float f) {
    __hip_bfloat16 h = __float2bfloat16(f);   // RNE
    return *reinterpret_cast<ushort*>(&h);
}

// async global->LDS, 16B per lane. LDS dest = wave-uniform base + lane*16.
__device__ __forceinline__ void glds16(const void* g, void* l) {
    __builtin_amdgcn_global_load_lds(
        (const __attribute__((address_space(1))) unsigned int*)g,
        (__attribute__((address_space(3))) unsigned int*)l, 16, 0, 0);
}

// ---------------------------------------------------------------------------
// Kernel 0: zero padded counters (16 ints at 64B stride)
// ---------------------------------------------------------------------------
__global__ void zero_k(int* __restrict__ cnt) {
    if (blockIdx.x == 0 && threadIdx.x < 256) cnt[threadIdx.x] = 0;
}

// ---------------------------------------------------------------------------
// Kernel 1: per-expert transpose + cvt: src [E][R][C] fp32 -> dst [E][C][R] bf16
// ---------------------------------------------------------------------------
__global__ __launch_bounds__(256) void trans_k(const float* __restrict__ src, ushort* __restrict__ dst,
                                               const int R, const int C) {
    const int e = blockIdx.z, r0 = blockIdx.y * 64, c0 = blockIdx.x * 64;
    __shared__ float t[64][65];
    const int tid = threadIdx.x;
    const int cseg = (tid & 15) * 4, rr = tid >> 4;
#pragma unroll
    for (int j = 0; j < 4; ++j) {
        const int r = rr + j * 16;
        const float4 v = *(const float4*)(src + ((size_t)e * R + r0 + r) * C + c0 + cseg);
        t[r][cseg] = v.x; t[r][cseg+1] = v.y; t[r][cseg+2] = v.z; t[r][cseg+3] = v.w;
    }
    __syncthreads();
    const int rseg = (tid & 15) * 4;
#pragma unroll
    for (int j = 0; j < 4; ++j) {
        const int crow = (tid >> 4) + j * 16;
        ushort o[4];
#pragma unroll
        for (int q = 0; q < 4; ++q) o[q] = f2bfu(t[rseg + q][crow]);
        *(uint2*)(dst + ((size_t)e * C + c0 + crow) * R + r0 + rseg) = *(uint2*)o;
    }
}

// ---------------------------------------------------------------------------
// Kernel 2: router (fp32 math) + x -> bf16 conversion fused.
// 4 tokens per wave: Wr/Wn rows are loaded once and reused across the 4
// tokens (cuts the per-token 64KB weight re-read 4x). Padded counters.
// entry = tok | gate_f16 << 16, appended to group g = expert*2 + slot.
// ---------------------------------------------------------------------------
__global__ __launch_bounds__(256) void router_k(
    const float* __restrict__ x, const float* __restrict__ Wr, const float* __restrict__ br,
    const float* __restrict__ Wn, const float* __restrict__ bn, const float* __restrict__ noise,
    int* __restrict__ cnt, unsigned* __restrict__ entries, ushort* __restrict__ xb)
{
    const int wave = threadIdx.x >> 6;
    const int lane = threadIdx.x & 63;
    const int t0 = (blockIdx.x * 4 + wave) * 4;     // 4 tokens per wave

    float accr[EE * 4], accn[EE * 4];               // [e][tk]
#pragma unroll
    for (int i = 0; i < EE * 4; ++i) { accr[i] = 0.f; accn[i] = 0.f; }

#pragma unroll 2
    for (int it = 0; it < DD / 64; ++it) {
        const int d = it * 64 + lane;
        float wr[8], wn[8];
        *(float4*)&wr[0] = *(const float4*)(Wr + (size_t)d * EE);
        *(float4*)&wr[4] = *(const float4*)(Wr + (size_t)d * EE + 4);
        *(float4*)&wn[0] = *(const float4*)(Wn + (size_t)d * EE);
        *(float4*)&wn[4] = *(const float4*)(Wn + (size_t)d * EE + 4);
        float xv[4];
#pragma unroll
        for (int tk = 0; tk < 4; ++tk) {
            xv[tk] = x[(size_t)(t0 + tk) * DD + d];
            xb[(size_t)(t0 + tk) * DD + d] = f2bfu(xv[tk]);
        }
#pragma unroll
        for (int e = 0; e < EE; ++e)
#pragma unroll
            for (int tk = 0; tk < 4; ++tk) {
                accr[e * 4 + tk] = fmaf(xv[tk], wr[e], accr[e * 4 + tk]);
                accn[e * 4 + tk] = fmaf(xv[tk], wn[e], accn[e * 4 + tk]);
            }
    }
#pragma unroll
    for (int off = 32; off > 0; off >>= 1) {
#pragma unroll
        for (int i = 0; i < EE * 4; ++i) {
            accr[i] += __shfl_xor(accr[i], off);
            accn[i] += __shfl_xor(accn[i], off);
        }
    }
    if (lane == 0) {
#pragma unroll
        for (int tk = 0; tk < 4; ++tk) {
            const int t = t0 + tk;
            float noisy[EE];
#pragma unroll
            for (int e = 0; e < EE; ++e) {
                const float lg = accr[e * 4 + tk] + br[e];
                const float nl = accn[e * 4 + tk] + bn[e];
                const float sp = fmaxf(nl, 0.f) + log1pf(expf(-fabsf(nl)));
                noisy[e] = lg + noise[(size_t)t * EE + e] * sp;
            }
            int i0 = 0;
#pragma unroll
            for (int e = 1; e < EE; ++e) if (noisy[e] > noisy[i0]) i0 = e;
            int i1 = (i0 == 0) ? 1 : 0;
#pragma unroll
            for (int e = 0; e < EE; ++e) if (e != i0 && noisy[e] > noisy[i1]) i1 = e;
            const float ex = expf(noisy[i1] - noisy[i0]);
            const float g0 = 1.f / (1.f + ex);
            const float g1 = ex / (1.f + ex);
            __half h0 = __float2half_rn(g0), h1 = __float2half_rn(g1);
            const unsigned u0 = (unsigned)t | ((unsigned)*reinterpret_cast<ushort*>(&h0) << 16);
            const unsigned u1 = (unsigned)t | ((unsigned)*reinterpret_cast<ushort*>(&h1) << 16);
            const int ga = i0 * 2 + 0, gb = i1 * 2 + 1;
            int p0 = atomicAdd(&cnt[ga * 16], 1);
            entries[ga * NTOK + p0] = u0;
            int p1 = atomicAdd(&cnt[gb * 16], 1);
            entries[gb * NTOK + p1] = u1;
        }
    }
}

// Kernel 3: exclusive prefix over 16 group counts
__global__ void offsets_k(const int* __restrict__ cnt, int* __restrict__ off) {
    if (threadIdx.x == 0 && blockIdx.x == 0) {
        int s = 0;
        for (int g = 0; g < NG; ++g) { off[g] = s; s += cnt[g * 16]; }
    }
}

// ---------------------------------------------------------------------------
// Grouped GEMM: 128x128x64 tile, 256 threads = 4 waves (2x2), each wave 64x64
// via 4x4 MFMA 16x16x32 frags over 2 k-halves. Tiles stored 128 rows x 8
// 16B-segs with XOR swizzle: phys_seg = log_seg ^ (row & 7) — zero bank
// conflicts (verified round 6: SQ_LDS_BANK_CONFLICT = 0).
// A-frag A[m=lane&15][k=(lane>>4)*8+j]; C/D col=lane&15, row=(lane>>4)*4+reg.
// ---------------------------------------------------------------------------

// Kernel 4: down: hid[off+row][n] = gelu(x_gathered @ WdT^T + bd)
__global__ __launch_bounds__(256) void down_k(
    const ushort* __restrict__ xb, const ushort* __restrict__ WdT, const float* __restrict__ bd,
    const int* __restrict__ cnt, const int* __restrict__ off,
    const unsigned* __restrict__ entries, ushort* __restrict__ hid)
{
    const int g = blockIdx.z, e = g >> 1;
    const int n_g = cnt[g * 16];
    const int tm = blockIdx.y;
    if (tm * 128 >= n_g) return;
    const int n0 = blockIdx.x * 128;

    __shared__ __align__(16) ushort As[128 * 64];
    __shared__ __align__(16) ushort Bs[128 * 64];
    __shared__ unsigned ecache[128];

    const int tid = threadIdx.x, lane = tid & 63, w = tid >> 6;
    const int wm = w >> 1, wn = w & 1;
    const int fr = lane & 15, fq = lane >> 4;

    if (tid < 128) {
        const int ridx = min(tm * 128 + tid, n_g - 1);
        ecache[tid] = entries[g * NTOK + ridx];
    }
    __syncthreads();

    const int lr = lane >> 3, seg = lane & 7;
    const int slog = seg ^ lr;                 // row&7 == lr for all j
    const ushort* gA[4]; const ushort* gB[4];
    char* lA[4]; char* lB[4];
    const ushort* WTe = WdT + (size_t)e * HH * DD;
#pragma unroll
    for (int j = 0; j < 4; ++j) {
        const int row = w * 32 + j * 8 + lr;
        const int tok = (int)(ecache[row] & 0xFFFFu);
        gA[j] = xb + (size_t)tok * DD + slog * 8;
        gB[j] = WTe + (size_t)(n0 + row) * DD + slog * 8;
        lA[j] = (char*)As + (size_t)(w * 256 + j * 64) * 16;
        lB[j] = (char*)Bs + (size_t)(w * 256 + j * 64) * 16;
    }

    floatx4 acc[4][4];
#pragma unroll
    for (int i = 0; i < 4; ++i)
#pragma unroll
        for (int j = 0; j < 4; ++j) acc[i][j] = (floatx4){0.f, 0.f, 0.f, 0.f};

    const int axr = wm * 64 + fr;
    const int bxr = wn * 64 + fr;

    for (int k0 = 0; k0 < DD; k0 += 64) {
        __syncthreads();
#pragma unroll
        for (int j = 0; j < 4; ++j) { glds16(gA[j] + k0, lA[j]); glds16(gB[j] + k0, lB[j]); }
        __syncthreads();
#pragma unroll
        for (int kh = 0; kh < 2; ++kh) {
            short8 a[4], b[4];
#pragma unroll
            for (int mt = 0; mt < 4; ++mt) {
                const int r = axr + mt * 16;
                a[mt] = *(const short8*)&As[r * 64 + ((kh * 4 + fq) ^ (r & 7)) * 8];
            }
#pragma unroll
            for (int nt = 0; nt < 4; ++nt) {
                const int r = bxr + nt * 16;
                b[nt] = *(const short8*)&Bs[r * 64 + ((kh * 4 + fq) ^ (r & 7)) * 8];
            }
#pragma unroll
            for (int mt = 0; mt < 4; ++mt)
#pragma unroll
                for (int nt = 0; nt < 4; ++nt)
                    acc[mt][nt] = __builtin_amdgcn_mfma_f32_16x16x32_bf16(a[mt], b[nt], acc[mt][nt], 0, 0, 0);
        }
    }

    const int hbase = off[g] + tm * 128;
#pragma unroll
    for (int nt = 0; nt < 4; ++nt) {
        const int n = n0 + wn * 64 + nt * 16 + fr;
        const float bias = bd[e * HH + n];
#pragma unroll
        for (int mt = 0; mt < 4; ++mt)
#pragma unroll
            for (int i = 0; i < 4; ++i) {
                const int rl = wm * 64 + mt * 16 + fq * 4 + i;
                if (tm * 128 + rl < n_g) {
                    const float v = acc[mt][nt][i] + bias;
                    const float ge = 0.5f * v * (1.f + erff(v * 0.7071067811865475f));
                    hid[(size_t)(hbase + rl) * HH + n] = f2bfu(ge);
                }
            }
    }
}

// Kernel 5: up: out[tok][n] (s=0: =, s=1: +=) (hid @ WuT^T + bu) * gate.
// Two passes: slot-0 groups cover every token exactly once (plain store);
// slot-1 pass does non-atomic RMW, ordered by the kernel boundary.
__global__ __launch_bounds__(256) void up_k(
    const ushort* __restrict__ hid, const ushort* __restrict__ WuT, const float* __restrict__ bu,
    const int* __restrict__ cnt, const int* __restrict__ off,
    const unsigned* __restrict__ entries, float* __restrict__ out, const int s)
{
    const int e = blockIdx.z, g = e * 2 + s;
    const int n_g = cnt[g * 16];
    const int tm = blockIdx.y;
    if (tm * 128 >= n_g) return;
    const int n0 = blockIdx.x * 128;

    __shared__ __align__(16) ushort As[128 * 64];
    __shared__ __align__(16) ushort Bs[128 * 64];
    __shared__ unsigned ecache[128];

    const int tid = threadIdx.x, lane = tid & 63, w = tid >> 6;
    const int wm = w >> 1, wn = w & 1;
    const int fr = lane & 15, fq = lane >> 4;

    if (tid < 128) {
        const int ridx = min(tm * 128 + tid, n_g - 1);
        ecache[tid] = entries[g * NTOK + ridx];
    }
    __syncthreads();

    const int lr = lane >> 3, seg = lane & 7;
    const int slog = seg ^ lr;
    const ushort* gA[4]; const ushort* gB[4];
    char* lA[4]; char* lB[4];
    const ushort* WTe = WuT + (size_t)e * DD * HH;
    const int hbase = off[g];
#pragma unroll
    for (int j = 0; j < 4; ++j) {
        const int row = w * 32 + j * 8 + lr;
        const int ar = min(tm * 128 + row, n_g - 1);
        gA[j] = hid + (size_t)(hbase + ar) * HH + slog * 8;
        gB[j] = WTe + (size_t)(n0 + row) * HH + slog * 8;
        lA[j] = (char*)As + (size_t)(w * 256 + j * 64) * 16;
        lB[j] = (char*)Bs + (size_t)(w * 256 + j * 64) * 16;
    }

    floatx4 acc[4][4];
#pragma unroll
    for (int i = 0; i < 4; ++i)
#pragma unroll
        for (int j = 0; j < 4; ++j) acc[i][j] = (floatx4){0.f, 0.f, 0.f, 0.f};

    const int axr = wm * 64 + fr;
    const int bxr = wn * 64 + fr;

    for (int k0 = 0; k0 < HH; k0 += 64) {
        __syncthreads();
#pragma unroll
        for (int j = 0; j < 4; ++j) { glds16(gA[j] + k0, lA[j]); glds16(gB[j] + k0, lB[j]); }
        __syncthreads();
#pragma unroll
        for (int kh = 0; kh < 2; ++kh) {
            short8 a[4], b[4];
#pragma unroll
            for (int mt = 0; mt < 4; ++mt) {
                const int r = axr + mt * 16;
                a[mt] = *(const short8*)&As[r * 64 + ((kh * 4 + fq) ^ (r & 7)) * 8];
            }
#pragma unroll
            for (int nt = 0; nt < 4; ++nt) {
                const int r = bxr + nt * 16;
                b[nt] = *(const short8*)&Bs[r * 64 + ((kh * 4 + fq) ^ (r & 7)) * 8];
            }
#pragma unroll
            for (int mt = 0; mt < 4; ++mt)
#pragma unroll
                for (int nt = 0; nt < 4; ++nt)
                    acc[mt][nt] = __builtin_amdgcn_mfma_f32_16x16x32_bf16(a[mt], b[nt], acc[mt][nt], 0, 0, 0);
        }
    }

#pragma unroll
    for (int nt = 0; nt < 4; ++nt) {
        const int n = n0 + wn * 64 + nt * 16 + fr;
        const float bias = bu[e * DD + n];
#pragma unroll
        for (int mt = 0; mt < 4; ++mt)
#pragma unroll
            for (int i = 0; i < 4; ++i) {
                const int rl = wm * 64 + mt * 16 + fq * 4 + i;
                if (tm * 128 + rl < n_g) {
                    const unsigned en = ecache[rl];
                    const int tok = (int)(en & 0xFFFFu);
                    ushort hb = (ushort)(en >> 16);
                    const float gate = __half2float(*reinterpret_cast<__half*>(&hb));
                    const float v = (acc[mt][nt][i] + bias) * gate;
                    float* op = out + (size_t)tok * DD + n;
                    if (s == 0) *op = v;
                    else        *op += v;
                }
            }
    }
}

// ---------------------------------------------------------------------------
// Workspace layout (bytes), total ~81 MB:
//   0         cnt    : int[16] @ 64B stride
//   1024      off    : int[16]
//   2048      entries: u32[16][16384]            (1 MB)
//   1050624   xb     : bf16 [16384][1024]        (32 MB)
//   34605056  WdT    : bf16 [8][512 h][1024 d]   (8 MB)
//   42993664  WuT    : bf16 [8][1024 d][512 h]   (8 MB)
//   51382272  hid    : bf16 [32768][512]         (32 MB)
// ---------------------------------------------------------------------------
extern "C" void kernel_launch(void* const* d_in, const int* in_sizes, int n_in,
                              void* d_out, int out_size, void* d_ws, size_t ws_size,
                              hipStream_t stream)
{
    const float* x     = (const float*)d_in[0];
    const float* Wr    = (const float*)d_in[1];
    const float* br    = (const float*)d_in[2];
    const float* Wn    = (const float*)d_in[3];
    const float* bn    = (const float*)d_in[4];
    const float* Wd    = (const float*)d_in[5];
    const float* bd    = (const float*)d_in[6];
    const float* Wu    = (const float*)d_in[7];
    const float* bu    = (const float*)d_in[8];
    const float* noise = (const float*)d_in[9];

    char* ws = (char*)d_ws;
    int*      cnt     = (int*)(ws + 0);
    int*      off     = (int*)(ws + 1024);
    unsigned* entries = (unsigned*)(ws + 2048);
    ushort*   xb      = (ushort*)(ws + 1050624);
    ushort*   WdT     = (ushort*)(ws + 34605056);
    ushort*   WuT     = (ushort*)(ws + 42993664);
    ushort*   hid     = (ushort*)(ws + 51382272);

    zero_k<<<1, 256, 0, stream>>>(cnt);
    trans_k<<<dim3(HH / 64, DD / 64, EE), 256, 0, stream>>>(Wd, WdT, DD, HH);  // [d][h]->[h][d]
    trans_k<<<dim3(DD / 64, HH / 64, EE), 256, 0, stream>>>(Wu, WuT, HH, DD);  // [h][d]->[d][h]
    router_k<<<NTOK / 16, 256, 0, stream>>>(x, Wr, br, Wn, bn, noise, cnt, entries, xb);
    offsets_k<<<1, 64, 0, stream>>>(cnt, off);
    down_k<<<dim3(HH / 128, MAXMT, NG), 256, 0, stream>>>(xb, WdT, bd, cnt, off, entries, hid);
    up_k<<<dim3(DD / 128, MAXMT, EE), 256, 0, stream>>>(hid, WuT, bu, cnt, off, entries, (float*)d_out, 0);
    up_k<<<dim3(DD / 128, MAXMT, EE), 256, 0, stream>>>(hid, WuT, bu, cnt, off, entries, (float*)d_out, 1);
}

// Round 8
// 446.151 us; speedup vs baseline: 1.1302x; 1.1302x over previous
//
#include <hip/hip_runtime.h>
#include <hip/hip_bf16.h>
#include <hip/hip_fp16.h>
#include <math.h>

// Problem constants
#define DD   1024
#define EE   8
#define HH   512
#define NTOK 16384        // B*T
#define NG   16           // (expert, slot) groups
#define MAXMT 24          // max 128-row tiles per group (n_g ~ 2048 +- ~200)

typedef __attribute__((ext_vector_type(8))) short short8;   // 8 bf16
typedef __attribute__((ext_vector_type(4))) float floatx4;  // MFMA C/D frag

__device__ __forceinline__ ushort f2bfu(float f) {
    __hip_bfloat16 h = __float2bfloat16(f);   // RNE
    return *reinterpret_cast<ushort*>(&h);
}
__device__ __forceinline__ float bfu2f(ushort u) {
    union { unsigned u; float f; } cv; cv.u = ((unsigned)u) << 16; return cv.f;
}

// async global->LDS, 16B per lane. LDS dest = wave-uniform base + lane*16.
__device__ __forceinline__ void glds16(const void* g, void* l) {
    __builtin_amdgcn_global_load_lds(
        (const __attribute__((address_space(1))) unsigned int*)g,
        (__attribute__((address_space(3))) unsigned int*)l, 16, 0, 0);
}

// ---------------------------------------------------------------------------
// Kernel 0: zero padded counters (16 ints at 64B stride)
// ---------------------------------------------------------------------------
__global__ void zero_k(int* __restrict__ cnt) {
    if (blockIdx.x == 0 && threadIdx.x < 256) cnt[threadIdx.x] = 0;
}

// ---------------------------------------------------------------------------
// Kernel 1: per-expert transpose + cvt: src [E][R][C] fp32 -> dst [E][C][R] bf16
// ---------------------------------------------------------------------------
__global__ __launch_bounds__(256) void trans_k(const float* __restrict__ src, ushort* __restrict__ dst,
                                               const int R, const int C) {
    const int e = blockIdx.z, r0 = blockIdx.y * 64, c0 = blockIdx.x * 64;
    __shared__ float t[64][65];
    const int tid = threadIdx.x;
    const int cseg = (tid & 15) * 4, rr = tid >> 4;
#pragma unroll
    for (int j = 0; j < 4; ++j) {
        const int r = rr + j * 16;
        const float4 v = *(const float4*)(src + ((size_t)e * R + r0 + r) * C + c0 + cseg);
        t[r][cseg] = v.x; t[r][cseg+1] = v.y; t[r][cseg+2] = v.z; t[r][cseg+3] = v.w;
    }
    __syncthreads();
    const int rseg = (tid & 15) * 4;
#pragma unroll
    for (int j = 0; j < 4; ++j) {
        const int crow = (tid >> 4) + j * 16;
        ushort o[4];
#pragma unroll
        for (int q = 0; q < 4; ++q) o[q] = f2bfu(t[rseg + q][crow]);
        *(uint2*)(dst + ((size_t)e * C + c0 + crow) * R + r0 + rseg) = *(uint2*)o;
    }
}

// ---------------------------------------------------------------------------
// Kernel 2: router (fp32 math) + x -> bf16 conversion fused. 1 token/wave
// (4-token variant regressed: 64 live accumulators -> latency-bound).
// entry = tok | gate_f16 << 16, appended to group g = expert*2 + slot.
// ---------------------------------------------------------------------------
__global__ __launch_bounds__(256) void router_k(
    const float* __restrict__ x, const float* __restrict__ Wr, const float* __restrict__ br,
    const float* __restrict__ Wn, const float* __restrict__ bn, const float* __restrict__ noise,
    int* __restrict__ cnt, unsigned* __restrict__ entries, ushort* __restrict__ xb)
{
    const int wave = threadIdx.x >> 6;
    const int lane = threadIdx.x & 63;
    const int t = blockIdx.x * 4 + wave;

    float accr[EE], accn[EE];
#pragma unroll
    for (int e = 0; e < EE; ++e) { accr[e] = 0.f; accn[e] = 0.f; }

    const float* xr = x + (size_t)t * DD;
    ushort* xbr = xb + (size_t)t * DD;
#pragma unroll 4
    for (int it = 0; it < DD / 64; ++it) {
        const int d = it * 64 + lane;
        const float xv = xr[d];
        xbr[d] = f2bfu(xv);                       // fused x -> bf16
        float wr[8], wn[8];
        *(float4*)&wr[0] = *(const float4*)(Wr + (size_t)d * EE);
        *(float4*)&wr[4] = *(const float4*)(Wr + (size_t)d * EE + 4);
        *(float4*)&wn[0] = *(const float4*)(Wn + (size_t)d * EE);
        *(float4*)&wn[4] = *(const float4*)(Wn + (size_t)d * EE + 4);
#pragma unroll
        for (int e = 0; e < EE; ++e) {
            accr[e] = fmaf(xv, wr[e], accr[e]);
            accn[e] = fmaf(xv, wn[e], accn[e]);
        }
    }
#pragma unroll
    for (int off = 32; off > 0; off >>= 1) {
#pragma unroll
        for (int e = 0; e < EE; ++e) {
            accr[e] += __shfl_xor(accr[e], off);
            accn[e] += __shfl_xor(accn[e], off);
        }
    }
    if (lane == 0) {
        float noisy[EE];
#pragma unroll
        for (int e = 0; e < EE; ++e) {
            const float lg = accr[e] + br[e];
            const float nl = accn[e] + bn[e];
            const float sp = fmaxf(nl, 0.f) + log1pf(expf(-fabsf(nl)));
            noisy[e] = lg + noise[(size_t)t * EE + e] * sp;
        }
        int i0 = 0;
#pragma unroll
        for (int e = 1; e < EE; ++e) if (noisy[e] > noisy[i0]) i0 = e;
        int i1 = (i0 == 0) ? 1 : 0;
#pragma unroll
        for (int e = 0; e < EE; ++e) if (e != i0 && noisy[e] > noisy[i1]) i1 = e;
        const float ex = expf(noisy[i1] - noisy[i0]);
        const float g0 = 1.f / (1.f + ex);
        const float g1 = ex / (1.f + ex);
        __half h0 = __float2half_rn(g0), h1 = __float2half_rn(g1);
        const unsigned u0 = (unsigned)t | ((unsigned)*reinterpret_cast<ushort*>(&h0) << 16);
        const unsigned u1 = (unsigned)t | ((unsigned)*reinterpret_cast<ushort*>(&h1) << 16);
        const int ga = i0 * 2 + 0, gb = i1 * 2 + 1;
        int p0 = atomicAdd(&cnt[ga * 16], 1);
        entries[ga * NTOK + p0] = u0;
        int p1 = atomicAdd(&cnt[gb * 16], 1);
        entries[gb * NTOK + p1] = u1;
    }
}

// Kernel 3: exclusive prefix over 16 group counts
__global__ void offsets_k(const int* __restrict__ cnt, int* __restrict__ off) {
    if (threadIdx.x == 0 && blockIdx.x == 0) {
        int s = 0;
        for (int g = 0; g < NG; ++g) { off[g] = s; s += cnt[g * 16]; }
    }
}

// ---------------------------------------------------------------------------
// Grouped GEMM: 128x128x64 tile, 4 waves (2x2), XOR-swizzled LDS (0 bank
// conflicts, verified r6). Flat 1-D grid with the N-slice in the LOW bits:
// if block->XCD assignment round-robins (bx % 8), all blocks reading a given
// weight N-slice land on one XCD -> slice fetched once per chip, and
// consecutive bx share the A-tile (L2 hits both ways).
// ---------------------------------------------------------------------------

// Kernel 4: down: hid[off+row][n] = gelu(x_gathered @ WdT^T + bd)
// grid: bx = ((g*MAXMT + tm)*4 + n0q), n0 = n0q*128
__global__ __launch_bounds__(256) void down_k(
    const ushort* __restrict__ xb, const ushort* __restrict__ WdT, const float* __restrict__ bd,
    const int* __restrict__ cnt, const int* __restrict__ off,
    const unsigned* __restrict__ entries, ushort* __restrict__ hid)
{
    const int bx = blockIdx.x;
    const int n0 = (bx & 3) * 128;
    const int tmg = bx >> 2;
    const int tm = tmg % MAXMT;
    const int g = tmg / MAXMT, e = g >> 1;
    const int n_g = cnt[g * 16];
    if (tm * 128 >= n_g) return;

    __shared__ __align__(16) ushort As[128 * 64];
    __shared__ __align__(16) ushort Bs[128 * 64];
    __shared__ unsigned ecache[128];

    const int tid = threadIdx.x, lane = tid & 63, w = tid >> 6;
    const int wm = w >> 1, wn = w & 1;
    const int fr = lane & 15, fq = lane >> 4;

    if (tid < 128) {
        const int ridx = min(tm * 128 + tid, n_g - 1);
        ecache[tid] = entries[g * NTOK + ridx];
    }
    __syncthreads();

    const int lr = lane >> 3, seg = lane & 7;
    const int slog = seg ^ lr;                 // row&7 == lr for all j
    const ushort* gA[4]; const ushort* gB[4];
    char* lA[4]; char* lB[4];
    const ushort* WTe = WdT + (size_t)e * HH * DD;
#pragma unroll
    for (int j = 0; j < 4; ++j) {
        const int row = w * 32 + j * 8 + lr;
        const int tok = (int)(ecache[row] & 0xFFFFu);
        gA[j] = xb + (size_t)tok * DD + slog * 8;
        gB[j] = WTe + (size_t)(n0 + row) * DD + slog * 8;
        lA[j] = (char*)As + (size_t)(w * 256 + j * 64) * 16;
        lB[j] = (char*)Bs + (size_t)(w * 256 + j * 64) * 16;
    }

    floatx4 acc[4][4];
#pragma unroll
    for (int i = 0; i < 4; ++i)
#pragma unroll
        for (int j = 0; j < 4; ++j) acc[i][j] = (floatx4){0.f, 0.f, 0.f, 0.f};

    const int axr = wm * 64 + fr;
    const int bxr = wn * 64 + fr;

    for (int k0 = 0; k0 < DD; k0 += 64) {
        __syncthreads();
#pragma unroll
        for (int j = 0; j < 4; ++j) { glds16(gA[j] + k0, lA[j]); glds16(gB[j] + k0, lB[j]); }
        __syncthreads();
#pragma unroll
        for (int kh = 0; kh < 2; ++kh) {
            short8 a[4], b[4];
#pragma unroll
            for (int mt = 0; mt < 4; ++mt) {
                const int r = axr + mt * 16;
                a[mt] = *(const short8*)&As[r * 64 + ((kh * 4 + fq) ^ (r & 7)) * 8];
            }
#pragma unroll
            for (int nt = 0; nt < 4; ++nt) {
                const int r = bxr + nt * 16;
                b[nt] = *(const short8*)&Bs[r * 64 + ((kh * 4 + fq) ^ (r & 7)) * 8];
            }
#pragma unroll
            for (int mt = 0; mt < 4; ++mt)
#pragma unroll
                for (int nt = 0; nt < 4; ++nt)
                    acc[mt][nt] = __builtin_amdgcn_mfma_f32_16x16x32_bf16(a[mt], b[nt], acc[mt][nt], 0, 0, 0);
        }
    }

    const int hbase = off[g] + tm * 128;
#pragma unroll
    for (int nt = 0; nt < 4; ++nt) {
        const int n = n0 + wn * 64 + nt * 16 + fr;
        const float bias = bd[e * HH + n];
#pragma unroll
        for (int mt = 0; mt < 4; ++mt)
#pragma unroll
            for (int i = 0; i < 4; ++i) {
                const int rl = wm * 64 + mt * 16 + fq * 4 + i;
                if (tm * 128 + rl < n_g) {
                    const float v = acc[mt][nt][i] + bias;
                    const float ge = 0.5f * v * (1.f + erff(v * 0.7071067811865475f));
                    hid[(size_t)(hbase + rl) * HH + n] = f2bfu(ge);
                }
            }
    }
}

// Kernel 5: up, SINGLE pass over all 16 groups:
//   slots[tok*2+slot][n] = (hid @ WuT^T + bu) * gate   (bf16, write-only)
// Every slot row is written exactly once -> no atomics, no RMW, no ordering.
// grid: bx = ((g*MAXMT + tm)*8 + n0q), n0 = n0q*128
__global__ __launch_bounds__(256) void up_k(
    const ushort* __restrict__ hid, const ushort* __restrict__ WuT, const float* __restrict__ bu,
    const int* __restrict__ cnt, const int* __restrict__ off,
    const unsigned* __restrict__ entries, ushort* __restrict__ slots)
{
    const int bx = blockIdx.x;
    const int n0 = (bx & 7) * 128;
    const int tmg = bx >> 3;
    const int tm = tmg % MAXMT;
    const int g = tmg / MAXMT, e = g >> 1, slot = g & 1;
    const int n_g = cnt[g * 16];
    if (tm * 128 >= n_g) return;

    __shared__ __align__(16) ushort As[128 * 64];
    __shared__ __align__(16) ushort Bs[128 * 64];
    __shared__ unsigned ecache[128];

    const int tid = threadIdx.x, lane = tid & 63, w = tid >> 6;
    const int wm = w >> 1, wn = w & 1;
    const int fr = lane & 15, fq = lane >> 4;

    if (tid < 128) {
        const int ridx = min(tm * 128 + tid, n_g - 1);
        ecache[tid] = entries[g * NTOK + ridx];
    }
    __syncthreads();

    const int lr = lane >> 3, seg = lane & 7;
    const int slog = seg ^ lr;
    const ushort* gA[4]; const ushort* gB[4];
    char* lA[4]; char* lB[4];
    const ushort* WTe = WuT + (size_t)e * DD * HH;
    const int hbase = off[g];
#pragma unroll
    for (int j = 0; j < 4; ++j) {
        const int row = w * 32 + j * 8 + lr;
        const int ar = min(tm * 128 + row, n_g - 1);
        gA[j] = hid + (size_t)(hbase + ar) * HH + slog * 8;
        gB[j] = WTe + (size_t)(n0 + row) * HH + slog * 8;
        lA[j] = (char*)As + (size_t)(w * 256 + j * 64) * 16;
        lB[j] = (char*)Bs + (size_t)(w * 256 + j * 64) * 16;
    }

    floatx4 acc[4][4];
#pragma unroll
    for (int i = 0; i < 4; ++i)
#pragma unroll
        for (int j = 0; j < 4; ++j) acc[i][j] = (floatx4){0.f, 0.f, 0.f, 0.f};

    const int axr = wm * 64 + fr;
    const int bxr = wn * 64 + fr;

    for (int k0 = 0; k0 < HH; k0 += 64) {
        __syncthreads();
#pragma unroll
        for (int j = 0; j < 4; ++j) { glds16(gA[j] + k0, lA[j]); glds16(gB[j] + k0, lB[j]); }
        __syncthreads();
#pragma unroll
        for (int kh = 0; kh < 2; ++kh) {
            short8 a[4], b[4];
#pragma unroll
            for (int mt = 0; mt < 4; ++mt) {
                const int r = axr + mt * 16;
                a[mt] = *(const short8*)&As[r * 64 + ((kh * 4 + fq) ^ (r & 7)) * 8];
            }
#pragma unroll
            for (int nt = 0; nt < 4; ++nt) {
                const int r = bxr + nt * 16;
                b[nt] = *(const short8*)&Bs[r * 64 + ((kh * 4 + fq) ^ (r & 7)) * 8];
            }
#pragma unroll
            for (int mt = 0; mt < 4; ++mt)
#pragma unroll
                for (int nt = 0; nt < 4; ++nt)
                    acc[mt][nt] = __builtin_amdgcn_mfma_f32_16x16x32_bf16(a[mt], b[nt], acc[mt][nt], 0, 0, 0);
        }
    }

#pragma unroll
    for (int nt = 0; nt < 4; ++nt) {
        const int n = n0 + wn * 64 + nt * 16 + fr;
        const float bias = bu[e * DD + n];
#pragma unroll
        for (int mt = 0; mt < 4; ++mt)
#pragma unroll
            for (int i = 0; i < 4; ++i) {
                const int rl = wm * 64 + mt * 16 + fq * 4 + i;
                if (tm * 128 + rl < n_g) {
                    const unsigned en = ecache[rl];
                    const int tok = (int)(en & 0xFFFFu);
                    ushort hb = (ushort)(en >> 16);
                    const float gate = __half2float(*reinterpret_cast<__half*>(&hb));
                    const float v = (acc[mt][nt][i] + bias) * gate;
                    slots[((size_t)tok * 2 + slot) * DD + n] = f2bfu(v);
                }
            }
    }
}

// Kernel 6: out[t][d] = slots[2t][d] + slots[2t+1][d]  (fp32 out, 8 elems/thread)
__global__ __launch_bounds__(256) void combine_k(
    const ushort* __restrict__ slots, float* __restrict__ out)
{
    const size_t flat = ((size_t)blockIdx.x * 256 + threadIdx.x) * 8;
    const size_t t = flat >> 10;         // / DD
    const size_t d = flat & (DD - 1);
    union { uint4 v; ushort h[8]; } a, b;
    a.v = *(const uint4*)(slots + ((t * 2 + 0) << 10) + d);
    b.v = *(const uint4*)(slots + ((t * 2 + 1) << 10) + d);
    float o[8];
#pragma unroll
    for (int j = 0; j < 8; ++j) o[j] = bfu2f(a.h[j]) + bfu2f(b.h[j]);
    *(float4*)(out + flat) = *(const float4*)&o[0];
    *(float4*)(out + flat + 4) = *(const float4*)&o[4];
}

// ---------------------------------------------------------------------------
// Workspace layout (bytes), total ~145 MB:
//   0         cnt    : int[16] @ 64B stride
//   1024      off    : int[16]
//   2048      entries: u32[16][16384]            (1 MB)
//   1050624   xb     : bf16 [16384][1024]        (32 MB)
//   34605056  WdT    : bf16 [8][512 h][1024 d]   (8 MB)
//   42993664  WuT    : bf16 [8][1024 d][512 h]   (8 MB)
//   51382272  hid    : bf16 [32768][512]         (32 MB)
//   84936704  slots  : bf16 [32768][1024]        (64 MB)
// ---------------------------------------------------------------------------
extern "C" void kernel_launch(void* const* d_in, const int* in_sizes, int n_in,
                              void* d_out, int out_size, void* d_ws, size_t ws_size,
                              hipStream_t stream)
{
    const float* x     = (const float*)d_in[0];
    const float* Wr    = (const float*)d_in[1];
    const float* br    = (const float*)d_in[2];
    const float* Wn    = (const float*)d_in[3];
    const float* bn    = (const float*)d_in[4];
    const float* Wd    = (const float*)d_in[5];
    const float* bd    = (const float*)d_in[6];
    const float* Wu    = (const float*)d_in[7];
    const float* bu    = (const float*)d_in[8];
    const float* noise = (const float*)d_in[9];

    char* ws = (char*)d_ws;
    int*      cnt     = (int*)(ws + 0);
    int*      off     = (int*)(ws + 1024);
    unsigned* entries = (unsigned*)(ws + 2048);
    ushort*   xb      = (ushort*)(ws + 1050624);
    ushort*   WdT     = (ushort*)(ws + 34605056);
    ushort*   WuT     = (ushort*)(ws + 42993664);
    ushort*   hid     = (ushort*)(ws + 51382272);
    ushort*   slots   = (ushort*)(ws + 84936704);

    zero_k<<<1, 256, 0, stream>>>(cnt);
    trans_k<<<dim3(HH / 64, DD / 64, EE), 256, 0, stream>>>(Wd, WdT, DD, HH);  // [d][h]->[h][d]
    trans_k<<<dim3(DD / 64, HH / 64, EE), 256, 0, stream>>>(Wu, WuT, HH, DD);  // [h][d]->[d][h]
    router_k<<<NTOK / 4, 256, 0, stream>>>(x, Wr, br, Wn, bn, noise, cnt, entries, xb);
    offsets_k<<<1, 64, 0, stream>>>(cnt, off);
    down_k<<<NG * MAXMT * 4, 256, 0, stream>>>(xb, WdT, bd, cnt, off, entries, hid);
    up_k<<<NG * MAXMT * 8, 256, 0, stream>>>(hid, WuT, bu, cnt, off, entries, slots);
    combine_k<<<(NTOK * DD) / (256 * 8), 256, 0, stream>>>(slots, (float*)d_out);
}